// Round 9
// baseline (207.666 us; speedup 1.0000x reference)
//
#include <hip/hip_runtime.h>

#define B_   32
#define S_   2048
#define D_   512
#define H_   32
#define BS_  (B_*S_)
#define NTILE_ (BS_/32)          // 2048 tiles of 32 rows
#define TPB_   4                 // tiles per block (pipelined, depth-2 prefetch)
#define GRID_  (NTILE_/TPB_)     // 512 blocks = 2 per CU
#define INV_SCALE 0.17677669529663689f   // 1/sqrt(32)

// workspace layout (bytes):
// [0, 32768):            PTF_g   ushort[16384]     fragment-contiguous bf16 projector
// [32768, 49152):        zdm     float2[2048]      per-tile (Z, DM) partials
// [49152, 4243456):      partial float[2048][512]  per-tile numerator partials

typedef short  s16x8 __attribute__((ext_vector_type(8)));
typedef float  f32x4 __attribute__((ext_vector_type(4)));

__device__ __forceinline__ float sigmoidf_(float x) {
    return 1.0f / (1.0f + __expf(-x));
}

__device__ __forceinline__ unsigned short f2bf(float f) {
    unsigned u = __float_as_uint(f);
    u += 0x7fffu + ((u >> 16) & 1u);     // round-to-nearest-even
    return (unsigned short)(u >> 16);
}

// LDS-ordering barrier that does NOT drain vmcnt: register-destined global
// prefetch loads stay in flight across it; the compiler's dataflow inserts
// incremental vmcnt(N) waits at first use of each prefetched value.
__device__ __forceinline__ void barrier_lds() {
    asm volatile("s_waitcnt lgkmcnt(0)" ::: "memory");
    __builtin_amdgcn_s_barrier();
    asm volatile("" ::: "memory");
}

// ---- projector -> fragment-contiguous bf16 layout ----
// PTF_g byte addr = ct*16384 + ks*1024 + lane*16 + e*2 holds
// bf16(proj[(lane>>4)*8 + ks*32 + e][ct*16 + (lane&15)]).
// A wave's 64 lanes then read consecutive 16B chunks per (ct,ks): stride-1,
// bank-conflict-free ds_read_b128 after a linear LDS stage.
__global__ void kTransposeBf(const float* __restrict__ P, unsigned short* __restrict__ PTF) {
    int o = blockIdx.x * 256 + threadIdx.x;      // 16384 total
    int ct = o >> 13;
    int r1 = o & 8191;
    int ks = r1 >> 9;
    int r2 = r1 & 511;
    int lane = r2 >> 3, e = r2 & 7;
    int row = (lane >> 4) * 8 + ks * 32 + e;
    int col = ct * 16 + (lane & 15);
    PTF[o] = f2bf(P[row * H_ + col]);
}

// ---- fused scores + unnormalized weighted partial sum ----
#define XST 520                               // bf16 row stride in LDS (512 + 8 pad)
#define WST 36                                // w0f row stride (floats), 16B rows

// __launch_bounds__(256,2): VGPR cap 256. Live set ~175 (tmpA+tmpB=128 +
// working ~45). R5 showed forcing 3 waves/EU spills tmp to scratch
// (WRITE_SIZE 4.3MB->82MB, kFused 119us at 0.7% MfmaUtil). Keep at 2.
__global__ __launch_bounds__(256, 2) void kFused(
        const float* __restrict__ inp, const int* __restrict__ mask,
        const unsigned short* __restrict__ PTFg, const float* __restrict__ hd,
        const float* __restrict__ ev,
        float* __restrict__ partial, float2* __restrict__ zdm) {
    __shared__ __align__(16) unsigned short xs[32 * XST];    // 33280 B
    __shared__ __align__(16) unsigned short ptf[16384];      // 32768 B B-fragments
    __shared__ __align__(16) float w0f[32 * WST];            // 4608 B
    __shared__ __align__(16) float hds[32 * 32];             // 4096 B hidden matrix
    __shared__ float cs[32];                  // m * exp(v)
    __shared__ float es[32];                  // exp(v)
    __shared__ float mskAll[TPB_ * 32];       // masks for all 4 tiles

    const int tid = threadIdx.x;
    const int wave = tid >> 6, lane = tid & 63;
    const int rt = wave & 1, ct = wave >> 1;
    const int m = lane & 15, quad = lane >> 4;
    const int k = tid & 31, slot = tid >> 5;
    const int tile0 = blockIdx.x * TPB_;

    // ---- depth-2 prefetch buffers: issue tiles 0 AND 1 immediately ----
    float4 tmpA[16], tmpB[16];                 // 128 VGPR
    {
        const float4* g0 = (const float4*)inp + (size_t)tile0 * 4096;
        #pragma unroll
        for (int i = 0; i < 16; ++i)
            tmpA[i] = g0[i * 256 + tid];       // flat index == row*128 + kq
        const float4* g1 = g0 + 4096;
        #pragma unroll
        for (int i = 0; i < 16; ++i)
            tmpB[i] = g1[i * 256 + tid];
    }

    // ---- stage PTF (32 KB linear copy), hds (4 KB), masks ----
    {
        const uint4* src = (const uint4*)PTFg;     // 2048 uint4
        uint4* dst = (uint4*)ptf;
        #pragma unroll
        for (int i = 0; i < 8; ++i)
            dst[i * 256 + tid] = src[i * 256 + tid];
    }
    ((float4*)hds)[tid] = ((const float4*)hd)[tid];    // exactly 256 f4
    const float evk = ev[k];
    if (tid < TPB_ * 32)
        mskAll[tid] = (mask[tile0 * 32 + tid] != 0) ? 1.0f : 0.0f;

    const unsigned short* bbase = ptf + ct * 8192 + lane * 8;  // wave's B column

    // ---- one tile: consume tc (tile t), prefetch tile t+2 back into tc ----
    auto tileBody = [&](float4 (&tc)[16], const int t) {
        const int tile = tile0 + t;
        const bool pf = (t + 2 < TPB_);
        const float4* g2 = (const float4*)inp + (size_t)(tile + 2) * 4096;

        // ---- stage tile t: bf16 convert + LDS write (incremental vmcnt) ----
        #pragma unroll
        for (int i = 0; i < 16; ++i) {
            int fi = i * 256 + tid;
            int row = fi >> 7, kq = fi & 127;
            unsigned p0, p1;                  // HW RNE pack
            asm("v_cvt_pk_bf16_f32 %0, %1, %2" : "=v"(p0) : "v"(tc[i].x), "v"(tc[i].y));
            asm("v_cvt_pk_bf16_f32 %0, %1, %2" : "=v"(p1) : "v"(tc[i].z), "v"(tc[i].w));
            uint2 u; u.x = p0; u.y = p1;
            *(uint2*)(xs + row * XST + kq * 4) = u;
        }

        // ---- prefetch group A (6/16): anti-convoy spread across phases ----
        if (pf) {
            #pragma unroll
            for (int i = 0; i < 6; ++i)
                tc[i] = g2[i * 256 + tid];
        }
        barrier_lds();                                  // (1) xs/ptf/hds ready

        // ---- MFMA: A from xs, B from ptf (both ds_read_b128, conflict-free) ----
        const unsigned short* arow = xs + (rt * 16 + m) * XST + quad * 8;
        f32x4 acc = {0.f, 0.f, 0.f, 0.f};
        #pragma unroll
        for (int ks = 0; ks < 16; ++ks) {
            s16x8 a = *(const s16x8*)(arow + ks * 32);
            s16x8 b = *(const s16x8*)(bbase + ks * 512);
            acc = __builtin_amdgcn_mfma_f32_16x16x32_bf16(a, b, acc, 0, 0, 0);
        }

        // epilogue: sigmoid(mask * score / sqrt(32)) -> w0f
        // C/D layout: col = lane&15, row = quad*4 + reg
        #pragma unroll
        for (int r = 0; r < 4; ++r) {
            int rowL = rt * 16 + quad * 4 + r;
            w0f[rowL * WST + ct * 16 + m] =
                sigmoidf_(mskAll[t * 32 + rowL] * acc[r] * INV_SCALE);
        }
        barrier_lds();                                  // (2) w0f ready

        // ---- prefetch group B (5/16) ----
        if (pf) {
            #pragma unroll
            for (int i = 6; i < 11; ++i)
                tc[i] = g2[i * 256 + tid];
        }

        // ---- hidden layer + evaluator fused, all 256 threads busy ----
        #pragma unroll
        for (int tt = 0; tt < 4; ++tt) {
            const int row = slot + 8 * tt;
            const float4* wr = (const float4*)(w0f + row * WST); // broadcast reads
            float s = 0.f;
            #pragma unroll
            for (int i = 0; i < 8; ++i) {
                float4 w4 = wr[i];
                s = fmaf(w4.x, hds[(4 * i + 0) * 32 + k], s);   // conflict-free LDS
                s = fmaf(w4.y, hds[(4 * i + 1) * 32 + k], s);
                s = fmaf(w4.z, hds[(4 * i + 2) * 32 + k], s);
                s = fmaf(w4.w, hds[(4 * i + 3) * 32 + k], s);
            }
            float val = sigmoidf_(s * INV_SCALE) * evk;   // w1[row][k] * ev[k]
            #pragma unroll
            for (int o = 1; o < 32; o <<= 1)              // sum over k (32-lane group)
                val += __shfl_xor(val, o);
            if (k == 0) {
                float v2 = sigmoidf_(val * INV_SCALE);    // in (0,1): exp safe
                float e  = __expf(v2);
                es[row] = e;
                cs[row] = mskAll[t * 32 + row] * e;
            }
        }
        barrier_lds();                                  // (3) cs/es ready

        // ---- prefetch group C (5/16) ----
        if (pf) {
            #pragma unroll
            for (int i = 11; i < 16; ++i)
                tc[i] = g2[i * 256 + tid];
        }

        // ---- tile (Z, DM) partial: wave 0 only ----
        if (tid < 64) {
            float z = 0.f, dm = 0.f;
            if (tid < 32) { z = es[tid]; dm = cs[tid]; }
            #pragma unroll
            for (int o = 32; o > 0; o >>= 1) {
                z  += __shfl_down(z, o);
                dm += __shfl_down(dm, o);
            }
            if (tid == 0) zdm[tile] = make_float2(z, dm);
        }

        // ---- numerator partial: thread owns d = {2*tid, 2*tid+1} ----
        float a0 = 0.f, a1 = 0.f;
        #pragma unroll 8
        for (int row = 0; row < 32; ++row) {
            unsigned u = *(const unsigned*)(xs + row * XST + 2 * tid); // conflict-free
            float x0 = __uint_as_float(u << 16);           // element 2*tid
            float x1 = __uint_as_float(u & 0xffff0000u);   // element 2*tid+1
            float c = cs[row];                              // broadcast
            a0 = fmaf(c, x0, a0);
            a1 = fmaf(c, x1, a1);
        }
        ((float2*)(partial + (size_t)tile * 512))[tid] = make_float2(a0, a1);

        barrier_lds();                                  // (4) xs reads done
    };

    // explicit call sites: tmp half selected at compile time (no dynamic
    // register-array indexing -> no scratch), TPB_ = 4
    tileBody(tmpA, 0);
    tileBody(tmpB, 1);
    tileBody(tmpA, 2);
    tileBody(tmpB, 3);
}

// ---- reduce 64 partials per b, normalize, write out ----
// 1024 threads: 4 groups of 256; each group sums 16 tiles. Every load is a
// contiguous 2 KiB per 256-thread group (coalesced), 16 loads in flight.
__global__ __launch_bounds__(1024) void kReduce(
        const float* __restrict__ partial, const float2* __restrict__ zdm,
        float* __restrict__ out) {
    const int b = blockIdx.x, tid = threadIdx.x;
    const int d2 = tid & 255;            // float2 column (2 d per thread)
    const int g  = tid >> 8;             // tile-group 0..3
    __shared__ float sInv;
    __shared__ float2 red[3][256];

    if (tid < 64) {
        float2 p = zdm[b * 64 + tid];
        float z = p.x, dm = p.y;
        #pragma unroll
        for (int o = 32; o > 0; o >>= 1) {
            z  += __shfl_down(z, o);
            dm += __shfl_down(dm, o);
        }
        if (tid == 0) sInv = 1.0f / (dm + 1e-12f * z);
    }

    const float2* pp = (const float2*)partial + (size_t)b * 64 * 256 + d2;
    float2 v[16];
    #pragma unroll
    for (int j = 0; j < 16; ++j)                     // 16 loads in flight
        v[j] = pp[(size_t)(g * 16 + j) * 256];
    float a = 0.f, c = 0.f;
    #pragma unroll
    for (int j = 0; j < 16; ++j) { a += v[j].x; c += v[j].y; }

    if (g) red[g - 1][d2] = make_float2(a, c);
    __syncthreads();
    if (g == 0) {
        #pragma unroll
        for (int q = 0; q < 3; ++q) { a += red[q][d2].x; c += red[q][d2].y; }
        const float inv = sInv;
        ((float2*)out)[b * 256 + d2] = make_float2(a * inv, c * inv);
    }
}

extern "C" void kernel_launch(void* const* d_in, const int* in_sizes, int n_in,
                              void* d_out, int out_size, void* d_ws, size_t ws_size,
                              hipStream_t stream) {
    const float* inp  = (const float*)d_in[0];
    const int*   mask = (const int*)d_in[1];
    const float* proj = (const float*)d_in[2];
    const float* hid  = (const float*)d_in[3];   // [1][32][32]
    const float* ev   = (const float*)d_in[4];   // [32]
    float* out = (float*)d_out;

    unsigned short* PTFg = (unsigned short*)d_ws;
    float2* zdm     = (float2*)((char*)d_ws + 32768);
    float*  partial = (float*)((char*)d_ws + 49152);

    kTransposeBf<<<64, 256, 0, stream>>>(proj, PTFg);
    kFused      <<<GRID_, 256, 0, stream>>>(inp, mask, PTFg, hid, ev, partial, zdm);
    kReduce     <<<B_, 1024, 0, stream>>>(partial, zdm, out);
}